// Round 1
// baseline (13390.411 us; speedup 1.0000x reference)
//
#include <hip/hip_runtime.h>
#include <math.h>

// Problem constants (fixed by the reference)
constexpr int Bb = 128, Tt = 24, Vv = 10000, Ee = 512, Hh = 512, Ff = 2048, Aa = 512, Pp = 196;
constexpr int XS = Ee + 2 * Hh; // 1536: per-(t,b) row = [h1n | emb | ctx]

// ---------------------------------------------------------------------------
// Generic tiled fp32 GEMM.
//  C[M,N] = A[M,K] @ B + bias1 + bias2  (B layout: NN = [K,N], BT(NT) = [N,K])
//  DUAL: adds A2[M,K2] @ B2 (same BT layout) — used for LSTM gate fusion.
//  REMAP: scatter rows (t*128+b) -> out[(b*T+t)*V + c] for the final fc.
// ---------------------------------------------------------------------------
template<int BM, int BN, int TM, int TN, bool BT, bool DUAL, bool REMAP>
__global__ __launch_bounds__(256) void gemm_kernel(
    const float* __restrict__ A, int lda,
    const float* __restrict__ B, int ldb, int K,
    const float* __restrict__ A2, int lda2,
    const float* __restrict__ B2, int ldb2, int K2,
    const float* __restrict__ bias1, const float* __restrict__ bias2,
    float* __restrict__ C, int ldc, int M, int N)
{
    constexpr int KT = 16;
    constexpr int PAD = 4; // keep row stride a multiple of 4 floats (16B) for vector LDS reads
    __shared__ float As[KT][BM + PAD];
    __shared__ float Bs[KT][BN + PAD];
    const int tid = threadIdx.x;
    const int tx = tid % (BN / TN);
    const int ty = tid / (BN / TN);
    const int m0 = blockIdx.y * BM;
    const int n0 = blockIdx.x * BN;

    float acc[TM][TN];
#pragma unroll
    for (int i = 0; i < TM; ++i)
#pragma unroll
        for (int j = 0; j < TN; ++j) acc[i][j] = 0.f;

    const int npass = DUAL ? 2 : 1;
    for (int pass = 0; pass < npass; ++pass) {
        const float* Ap = (DUAL && pass) ? A2 : A;
        const float* Bp = (DUAL && pass) ? B2 : B;
        const int ldap = (DUAL && pass) ? lda2 : lda;
        const int ldbp = (DUAL && pass) ? ldb2 : ldb;
        const int Kp   = (DUAL && pass) ? K2 : K;   // all K's used are multiples of 16

        for (int k0 = 0; k0 < Kp; k0 += KT) {
            // A tile: As[k][m] = Ap[(m0+m)*lda + k0+k]; k fastest -> coalesced
#pragma unroll
            for (int l = tid; l < BM * KT; l += 256) {
                int k = l % KT, m = l / KT;
                int gm = m0 + m;
                As[k][m] = (gm < M) ? Ap[(size_t)gm * ldap + k0 + k] : 0.f;
            }
            if (BT) { // B is [N,K]
#pragma unroll
                for (int l = tid; l < BN * KT; l += 256) {
                    int k = l % KT, n = l / KT;
                    int gn = n0 + n;
                    Bs[k][n] = (gn < N) ? Bp[(size_t)gn * ldbp + k0 + k] : 0.f;
                }
            } else {  // B is [K,N]
#pragma unroll
                for (int l = tid; l < BN * KT; l += 256) {
                    int n = l % BN, k = l / BN;
                    int gn = n0 + n;
                    Bs[k][n] = (gn < N) ? Bp[(size_t)(k0 + k) * ldbp + gn] : 0.f;
                }
            }
            __syncthreads();
#pragma unroll
            for (int k = 0; k < KT; ++k) {
                float a[TM], b[TN];
#pragma unroll
                for (int i = 0; i < TM; ++i) a[i] = As[k][ty * TM + i];
#pragma unroll
                for (int j = 0; j < TN; ++j) b[j] = Bs[k][tx * TN + j];
#pragma unroll
                for (int i = 0; i < TM; ++i)
#pragma unroll
                    for (int j = 0; j < TN; ++j) acc[i][j] += a[i] * b[j];
            }
            __syncthreads();
        }
    }

#pragma unroll
    for (int i = 0; i < TM; ++i) {
        int r = m0 + ty * TM + i;
        if (r >= M) continue;
#pragma unroll
        for (int j = 0; j < TN; ++j) {
            int c = n0 + tx * TN + j;
            if (c >= N) continue;
            float v = acc[i][j];
            if (bias1) v += bias1[c];
            if (bias2) v += bias2[c];
            if (REMAP) {
                int t = r >> 7, b = r & 127; // rows are (t*128 + b)
                C[((size_t)(b * Tt + t)) * Vv + c] = v;
            } else {
                C[(size_t)r * ldc + c] = v;
            }
        }
    }
}

// ---------------------------------------------------------------------------
// Fused per-step attention: one block per batch row b.
//  att_h = h1[b] @ att_Wh + att_bh                     (coalesced column GEMV)
//  scores[p] = sum_a tanh(feat_att[b,p,a]+att_h[a])*att_v[a] + att_bv
//  alpha = softmax(scores); ctx = relu(alpha @ fproj[b] + proj_b)
//  writes ctx into xs_t[b, 1024:1536]
// ---------------------------------------------------------------------------
__global__ __launch_bounds__(256) void attention_step_kernel(
    const float* __restrict__ feat_att, // [B,P,A]
    const float* __restrict__ fproj,    // [B,P,H] (no bias)
    const float* __restrict__ h1,       // [B,H]
    const float* __restrict__ att_Wh,   // [H,A]
    const float* __restrict__ att_bh,   // [A]
    const float* __restrict__ att_v,    // [A]
    const float* __restrict__ att_bv,   // [1]
    const float* __restrict__ proj_b,   // [H]
    float* __restrict__ xs_t)           // [B,1536]
{
    __shared__ float h1s[Hh];
    __shared__ float atth[Aa];
    __shared__ float sc[Pp];
    const int b = blockIdx.x;
    const int tid = threadIdx.x;
    const int lane = tid & 63;
    const int wave = tid >> 6;

    for (int i = tid; i < Hh; i += 256) h1s[i] = h1[b * Hh + i];
    __syncthreads();

    for (int a = tid; a < Aa; a += 256) {
        float s = att_bh[a];
        for (int k = 0; k < Hh; ++k) s += h1s[k] * att_Wh[k * Aa + a];
        atth[a] = s;
    }
    __syncthreads();

    const float* fa = feat_att + (size_t)b * Pp * Aa;
    for (int p = wave; p < Pp; p += 4) {
        float partial = 0.f;
        for (int a = lane; a < Aa; a += 64)
            partial += tanhf(fa[p * Aa + a] + atth[a]) * att_v[a];
#pragma unroll
        for (int o = 32; o > 0; o >>= 1) partial += __shfl_down(partial, o);
        if (lane == 0) sc[p] = partial + att_bv[0];
    }
    __syncthreads();

    if (tid < 64) { // single-wave softmax over P=196
        float m = -1e30f;
        for (int p = lane; p < Pp; p += 64) m = fmaxf(m, sc[p]);
#pragma unroll
        for (int o = 32; o > 0; o >>= 1) m = fmaxf(m, __shfl_down(m, o));
        m = __shfl(m, 0);
        float s = 0.f;
        for (int p = lane; p < Pp; p += 64) { float e = expf(sc[p] - m); sc[p] = e; s += e; }
#pragma unroll
        for (int o = 32; o > 0; o >>= 1) s += __shfl_down(s, o);
        s = __shfl(s, 0);
        float inv = 1.f / s;
        for (int p = lane; p < Pp; p += 64) sc[p] *= inv;
    }
    __syncthreads();

    const float* fp = fproj + (size_t)b * Pp * Hh;
    for (int h = tid; h < Hh; h += 256) {
        float accv = 0.f;
        for (int p = 0; p < Pp; ++p) accv += sc[p] * fp[p * Hh + h];
        accv += proj_b[h];
        xs_t[b * XS + Ee + Hh + h] = fmaxf(accv, 0.f); // ctx slot [1024:1536]
    }
}

// ---------------------------------------------------------------------------
__device__ __forceinline__ float sigmoidf_(float x) { return 1.f / (1.f + expf(-x)); }

__global__ __launch_bounds__(256) void lstm_pointwise_kernel(
    const float* __restrict__ gates, // [B,4H] in PyTorch order i,f,g,o
    float* __restrict__ c_state,     // [B,H] in/out
    float* __restrict__ h_state,     // [B,H] out
    float* __restrict__ h_copy, int h_copy_ld)
{
    int idx = blockIdx.x * 256 + threadIdx.x;
    if (idx >= Bb * Hh) return;
    int b = idx / Hh, j = idx % Hh;
    const float* g = gates + (size_t)b * 4 * Hh;
    float i_ = sigmoidf_(g[j]);
    float f_ = sigmoidf_(g[Hh + j]);
    float gg = tanhf(g[2 * Hh + j]);
    float o_ = sigmoidf_(g[3 * Hh + j]);
    float c = f_ * c_state[idx] + i_ * gg;
    c_state[idx] = c;
    float h = o_ * tanhf(c);
    h_state[idx] = h;
    if (h_copy) h_copy[(size_t)b * h_copy_ld + j] = h;
}

// ---------------------------------------------------------------------------
__global__ __launch_bounds__(256) void emb_fill_kernel(
    const float* __restrict__ emb, const int* __restrict__ captions,
    float* __restrict__ xs) // [T,B,1536], emb slot [512:1024]
{
    int idx = blockIdx.x * 256 + threadIdx.x;
    if (idx >= Tt * Bb * Ee) return;
    int e = idx % Ee;
    int rb = idx / Ee;
    int t = rb / Bb;
    int b = rb % Bb;
    int tok = captions[b * Tt + t];
    xs[((size_t)(t * Bb + b)) * XS + Ee + e] = emb[(size_t)tok * Ee + e];
}

// ---------------------------------------------------------------------------
__global__ __launch_bounds__(256) void layernorm_kernel(
    const float* __restrict__ x, const float* __restrict__ g,
    const float* __restrict__ beta, float* __restrict__ y) // rows of 512
{
    __shared__ float red[8];
    const int row = blockIdx.x;
    const float* xr = x + (size_t)row * Hh;
    const int tid = threadIdx.x, lane = tid & 63, wave = tid >> 6;
    float v0 = xr[tid], v1 = xr[tid + 256];
    float s = v0 + v1;
#pragma unroll
    for (int o = 32; o > 0; o >>= 1) s += __shfl_down(s, o);
    if (lane == 0) red[wave] = s;
    __syncthreads();
    float mu = (red[0] + red[1] + red[2] + red[3]) / 512.f;
    float d0 = v0 - mu, d1 = v1 - mu;
    float q = d0 * d0 + d1 * d1;
#pragma unroll
    for (int o = 32; o > 0; o >>= 1) q += __shfl_down(q, o);
    __syncthreads();
    if (lane == 0) red[wave] = q;
    __syncthreads();
    float var = (red[0] + red[1] + red[2] + red[3]) / 512.f;
    float inv = 1.f / sqrtf(var + 1e-5f);
    y[(size_t)row * Hh + tid]       = d0 * inv * g[tid] + beta[tid];
    y[(size_t)row * Hh + tid + 256] = d1 * inv * g[tid + 256] + beta[tid + 256];
}

// ---------------------------------------------------------------------------
extern "C" void kernel_launch(void* const* d_in, const int* in_sizes, int n_in,
                              void* d_out, int out_size, void* d_ws, size_t ws_size,
                              hipStream_t stream)
{
    const float* features = (const float*)d_in[0];
    const int*   captions = (const int*)d_in[1];
    const float* emb      = (const float*)d_in[2];
    const float* att_Wf   = (const float*)d_in[3];
    const float* att_bf   = (const float*)d_in[4];
    const float* att_Wh   = (const float*)d_in[5];
    const float* att_bh   = (const float*)d_in[6];
    const float* att_v    = (const float*)d_in[7];
    const float* att_bv   = (const float*)d_in[8];
    const float* proj_W   = (const float*)d_in[9];
    const float* proj_b   = (const float*)d_in[10];
    const float* W_ih0    = (const float*)d_in[11];
    const float* W_hh0    = (const float*)d_in[12];
    const float* b_ih0    = (const float*)d_in[13];
    const float* b_hh0    = (const float*)d_in[14];
    const float* W_ih1    = (const float*)d_in[15];
    const float* W_hh1    = (const float*)d_in[16];
    const float* b_ih1    = (const float*)d_in[17];
    const float* b_hh1    = (const float*)d_in[18];
    const float* ln_g     = (const float*)d_in[19];
    const float* ln_b     = (const float*)d_in[20];
    const float* skip_W   = (const float*)d_in[21];
    const float* skip_b   = (const float*)d_in[22];
    const float* fc_W     = (const float*)d_in[23];
    const float* fc_b     = (const float*)d_in[24];

    // Workspace carve-up (~136 MB fp32)
    float* ws = (float*)d_ws;
    size_t off = 0;
    auto alloc = [&](size_t n) { float* p = ws + off; off += (n + 63) & ~(size_t)63; return p; };
    float* feat_att = alloc((size_t)Bb * Pp * Aa);   // [B*P, A]
    float* fproj    = alloc((size_t)Bb * Pp * Hh);   // [B*P, H]
    float* xs       = alloc((size_t)Tt * Bb * XS);   // [T,B,1536] = [h1n|emb|ctx]
    float* gates    = alloc((size_t)Bb * 4 * Hh);    // [B,2048]
    float* h0 = alloc((size_t)Bb * Hh);
    float* c0 = alloc((size_t)Bb * Hh);
    float* h1 = alloc((size_t)Bb * Hh);
    float* c1 = alloc((size_t)Bb * Hh);
    float* skip_pre = alloc((size_t)Tt * Bb * Hh);
    float* ln_all   = alloc((size_t)Tt * Bb * Hh);

    // Zero LSTM states (h0,c0,h1,c1 are contiguous; ws is poisoned each call)
    hipMemsetAsync(h0, 0, (size_t)4 * Bb * Hh * sizeof(float), stream);

    dim3 blk(256);

    // feat_att = features @ att_Wf + att_bf : [25088,2048]@[2048,512]
    gemm_kernel<64, 64, 4, 4, false, false, false><<<dim3(Aa / 64, (Bb * Pp) / 64), blk, 0, stream>>>(
        features, Ff, att_Wf, Aa, Ff,
        nullptr, 0, nullptr, 0, 0,
        att_bf, nullptr, feat_att, Aa, Bb * Pp, Aa);

    // fproj = features @ proj_W (bias applied post-softmax-reduce)
    gemm_kernel<64, 64, 4, 4, false, false, false><<<dim3(Hh / 64, (Bb * Pp) / 64), blk, 0, stream>>>(
        features, Ff, proj_W, Hh, Ff,
        nullptr, 0, nullptr, 0, 0,
        nullptr, nullptr, fproj, Hh, Bb * Pp, Hh);

    emb_fill_kernel<<<(Tt * Bb * Ee + 255) / 256, blk, 0, stream>>>(emb, captions, xs);

    for (int t = 0; t < Tt; ++t) {
        float* xs_t = xs + (size_t)t * Bb * XS;

        attention_step_kernel<<<Bb, blk, 0, stream>>>(
            feat_att, fproj, h1, att_Wh, att_bh, att_v, att_bv, proj_b, xs_t);

        // gates0 = x@W_ih0^T + h0@W_hh0^T + b_ih0 + b_hh0 ; x = xs_t[:,512:1536]
        gemm_kernel<32, 32, 2, 2, true, true, false><<<dim3(2048 / 32, Bb / 32), blk, 0, stream>>>(
            xs_t + Ee, XS, W_ih0, Ee + Hh, Ee + Hh,
            h0, Hh, W_hh0, Hh, Hh,
            b_ih0, b_hh0, gates, 4 * Hh, Bb, 4 * Hh);

        lstm_pointwise_kernel<<<(Bb * Hh + 255) / 256, blk, 0, stream>>>(gates, c0, h0, nullptr, 0);

        // gates1 = h0n@W_ih1^T + h1@W_hh1^T + b_ih1 + b_hh1
        gemm_kernel<32, 32, 2, 2, true, true, false><<<dim3(2048 / 32, Bb / 32), blk, 0, stream>>>(
            h0, Hh, W_ih1, Hh, Hh,
            h1, Hh, W_hh1, Hh, Hh,
            b_ih1, b_hh1, gates, 4 * Hh, Bb, 4 * Hh);

        // writes h1n into both the recurrent state and xs_t[:,0:512] (skip input)
        lstm_pointwise_kernel<<<(Bb * Hh + 255) / 256, blk, 0, stream>>>(gates, c1, h1, xs_t, XS);
    }

    // skip = xs @ skip_W + skip_b : [3072,1536]@[1536,512]
    gemm_kernel<64, 64, 4, 4, false, false, false><<<dim3(Hh / 64, (Tt * Bb) / 64), blk, 0, stream>>>(
        xs, XS, skip_W, Hh, XS,
        nullptr, 0, nullptr, 0, 0,
        skip_b, nullptr, skip_pre, Hh, Tt * Bb, Hh);

    layernorm_kernel<<<Tt * Bb, blk, 0, stream>>>(skip_pre, ln_g, ln_b, ln_all);

    // out = ln @ fc_W + fc_b : [3072,512]@[512,10000], remapped to [B,T,V]
    gemm_kernel<64, 64, 4, 4, false, false, true><<<dim3((Vv + 63) / 64, (Tt * Bb) / 64), blk, 0, stream>>>(
        ln_all, Hh, fc_W, Vv, Hh,
        nullptr, 0, nullptr, 0, 0,
        fc_b, nullptr, (float*)d_out, Vv, Tt * Bb, Vv);
}

// Round 2
// 5231.056 us; speedup vs baseline: 2.5598x; 2.5598x over previous
//
#include <hip/hip_runtime.h>
#include <hip/hip_bf16.h>
#include <math.h>

constexpr int Bb = 128, Tt = 24, Vv = 10000, Ee = 512, Hh = 512, Ff = 2048, Aa = 512, Pp = 196;
constexpr int XS = Ee + 2 * Hh; // 1536: per-(t,b) row = [h1 | emb | ctx]

typedef __attribute__((ext_vector_type(8))) short bhalf8;   // 8 bf16 = 4 VGPRs (MFMA A/B frag)
typedef __attribute__((ext_vector_type(4))) float fx4;      // MFMA C/D frag

__device__ __forceinline__ ushort f2bf(float f) {
    __hip_bfloat16 h = __float2bfloat16(f);
    return *reinterpret_cast<ushort*>(&h);
}
__device__ __forceinline__ float bf2f(ushort u) {
    __hip_bfloat16 h = *reinterpret_cast<__hip_bfloat16*>(&u);
    return __bfloat162float(h);
}
__device__ __forceinline__ float sigm_(float x) { return 1.f / (1.f + __expf(-x)); }
__device__ __forceinline__ float tanh_(float x) {
    x = fminf(fmaxf(x, -15.f), 15.f);
    float e = __expf(2.f * x);
    return (e - 1.f) / (e + 1.f);
}

// ---------------------------------------------------------------------------
// Direct-load bf16 MFMA GEMM: C[M,N] = A[M,K] @ B[N,K]^T + bias1 + bias2
// wave tile 16m x 64n (4 frags), block = 4 waves stacked in m -> 64m x 64n.
// grid.x = m-tiles (m-major => same-m blocks land on same XCD for A-reuse),
// grid.y = n-tiles.
// A frag layout: A[m=lane&15][k=quad*8+j]; B^T frag: row n=lane&15, same k.
// C/D: col=lane&15, row=quad*4+reg  [verified mapping, learn_hip m89/m91]
// OUT_MODE: 0 = fp32 store, 1 = bf16 store, 2 = fp32 store remapped (t*128+b
// row -> out[(b*T+t)*V + col]) with col<N guard (fc tail).
// ---------------------------------------------------------------------------
template<bool AFP32, int OUT_MODE>
__global__ __launch_bounds__(256) void mfma_gemm(
    const void* __restrict__ Av, int lda,
    const ushort* __restrict__ B, int ldb, int K,
    const float* __restrict__ bias1, const float* __restrict__ bias2,
    void* __restrict__ Cv, int ldc, int N)
{
    const int lane = threadIdx.x & 63, wave = threadIdx.x >> 6;
    const int row16 = lane & 15, quad = lane >> 4;
    const int m0 = blockIdx.x * 64 + wave * 16;
    const int n0 = blockIdx.y * 64;

    const ushort* A16 = nullptr; const float* A32 = nullptr;
    if (AFP32) A32 = (const float*)Av + (size_t)(m0 + row16) * lda + quad * 8;
    else       A16 = (const ushort*)Av + (size_t)(m0 + row16) * lda + quad * 8;

    const ushort* Bp[4];
#pragma unroll
    for (int f = 0; f < 4; ++f) {
        int n = n0 + 16 * f + row16;
        if (OUT_MODE == 2 && n >= N) n = N - 1; // clamp (stores guarded)
        Bp[f] = B + (size_t)n * ldb + quad * 8;
    }

    fx4 acc[4] = {fx4{0,0,0,0}, fx4{0,0,0,0}, fx4{0,0,0,0}, fx4{0,0,0,0}};

#pragma unroll 2
    for (int k0 = 0; k0 < K; k0 += 32) {
        bhalf8 a;
        if (AFP32) {
            fx4 u0 = *(const fx4*)(A32 + k0);
            fx4 u1 = *(const fx4*)(A32 + k0 + 4);
#pragma unroll
            for (int j = 0; j < 4; ++j) { a[j] = (short)f2bf(u0[j]); a[4 + j] = (short)f2bf(u1[j]); }
        } else {
            a = *(const bhalf8*)(A16 + k0);
        }
#pragma unroll
        for (int f = 0; f < 4; ++f) {
            bhalf8 b = *(const bhalf8*)(Bp[f] + k0);
            acc[f] = __builtin_amdgcn_mfma_f32_16x16x32_bf16(a, b, acc[f], 0, 0, 0);
        }
    }

#pragma unroll
    for (int f = 0; f < 4; ++f) {
        int col = n0 + 16 * f + row16;
        if (OUT_MODE == 2 && col >= N) continue;
        float badd = (bias1 ? bias1[col] : 0.f) + (bias2 ? bias2[col] : 0.f);
#pragma unroll
        for (int r = 0; r < 4; ++r) {
            int m = m0 + quad * 4 + r;
            float v = acc[f][r] + badd;
            if (OUT_MODE == 0)      ((float*)Cv)[(size_t)m * ldc + col] = v;
            else if (OUT_MODE == 1) ((ushort*)Cv)[(size_t)m * ldc + col] = f2bf(v);
            else { int t = m >> 7, b = m & 127; ((float*)Cv)[((size_t)(b * Tt + t)) * Vv + col] = v; }
        }
    }
}

// ---------------------------------------------------------------------------
// Fused dual-GEMM + LSTM cell. gates[128, 4*512] = A1@B1^T + A2@B2^T (+pre or
// biases). Gate-interleaved mapping: block covers j0..j0+16, frag f = gate f,
// so each lane holds i,f,g,o for its (b,j) pairs entirely in registers.
// Epilogue: c = sig(f)*c + sig(i)*tanh(g); h = sig(o)*tanh(c).
// Writes c (fp32, in-place) and h (bf16, ping-pong buffer; optional xs slot).
// grid: (m-tiles = 2, j-tiles = 32) = 64 blocks.
// ---------------------------------------------------------------------------
template<bool HAS_PRE>
__global__ __launch_bounds__(256) void gates_cell_kernel(
    const ushort* __restrict__ A1, int lda1, const ushort* __restrict__ B1,
    const ushort* __restrict__ A2, const ushort* __restrict__ B2,
    const float* __restrict__ pre,      // [128, 2048] incl. biases (layer0)
    const float* __restrict__ bias_a, const float* __restrict__ bias_b, // layer1
    float* __restrict__ cstate,         // [128,512] fp32 in/out
    ushort* __restrict__ hout,          // [128,512] bf16 (write buffer != read)
    ushort* __restrict__ xs_slot)       // optional [.,XS] h copy, may be null
{
    const int lane = threadIdx.x & 63, wave = threadIdx.x >> 6;
    const int row16 = lane & 15, quad = lane >> 4;
    const int m0 = blockIdx.x * 64 + wave * 16;
    const int j0 = blockIdx.y * 16;

    const ushort* a1p = A1 + (size_t)(m0 + row16) * lda1 + quad * 8;
    const ushort* a2p = A2 + (size_t)(m0 + row16) * Hh + quad * 8;
    const ushort *b1p[4], *b2p[4];
#pragma unroll
    for (int f = 0; f < 4; ++f) {
        int bn = f * Hh + j0 + row16;          // W row = gate*512 + j
        b1p[f] = B1 + (size_t)bn * Hh + quad * 8;
        b2p[f] = B2 + (size_t)bn * Hh + quad * 8;
    }

    fx4 acc[4] = {fx4{0,0,0,0}, fx4{0,0,0,0}, fx4{0,0,0,0}, fx4{0,0,0,0}};
#pragma unroll 2
    for (int k0 = 0; k0 < Hh; k0 += 32) {
        bhalf8 a = *(const bhalf8*)(a1p + k0);
#pragma unroll
        for (int f = 0; f < 4; ++f)
            acc[f] = __builtin_amdgcn_mfma_f32_16x16x32_bf16(a, *(const bhalf8*)(b1p[f] + k0), acc[f], 0, 0, 0);
    }
#pragma unroll 2
    for (int k0 = 0; k0 < Hh; k0 += 32) {
        bhalf8 a = *(const bhalf8*)(a2p + k0);
#pragma unroll
        for (int f = 0; f < 4; ++f)
            acc[f] = __builtin_amdgcn_mfma_f32_16x16x32_bf16(a, *(const bhalf8*)(b2p[f] + k0), acc[f], 0, 0, 0);
    }

    const int j = j0 + row16;
#pragma unroll
    for (int r = 0; r < 4; ++r) {
        int b = m0 + quad * 4 + r;
        float gi = acc[0][r], gf = acc[1][r], gg = acc[2][r], go = acc[3][r];
        if (HAS_PRE) {
            const float* pr = pre + (size_t)b * (4 * Hh) + j;
            gi += pr[0]; gf += pr[Hh]; gg += pr[2 * Hh]; go += pr[3 * Hh];
        } else {
            gi += bias_a[j] + bias_b[j];
            gf += bias_a[Hh + j] + bias_b[Hh + j];
            gg += bias_a[2 * Hh + j] + bias_b[2 * Hh + j];
            go += bias_a[3 * Hh + j] + bias_b[3 * Hh + j];
        }
        int idx = b * Hh + j;
        float c = sigm_(gf) * cstate[idx] + sigm_(gi) * tanh_(gg);
        cstate[idx] = c;
        float h = sigm_(go) * tanh_(c);
        hout[idx] = f2bf(h);
        if (xs_slot) xs_slot[(size_t)b * XS + j] = f2bf(h);
    }
}

// ---------------------------------------------------------------------------
// Per-step attention, one block per batch row. bf16 activations, fp32 math.
// ---------------------------------------------------------------------------
__global__ __launch_bounds__(256) void attention_step_kernel(
    const ushort* __restrict__ feat_att, // [B,P,A] bf16
    const ushort* __restrict__ fproj,    // [B,P,H] bf16
    const ushort* __restrict__ h1b,      // [B,H] bf16
    const ushort* __restrict__ attWh_t,  // [A,H] bf16 (transposed)
    const float* __restrict__ att_bh, const float* __restrict__ att_v,
    const float* __restrict__ att_bv, const float* __restrict__ proj_b,
    ushort* __restrict__ xs_t)           // [B,XS], ctx -> cols [1024,1536)
{
    __shared__ float h1s[Hh];
    __shared__ float atth[Aa];
    __shared__ float sc[200];
    const int b = blockIdx.x, tid = threadIdx.x;
    const int lane = tid & 63, wave = tid >> 6;

    for (int i = tid; i < Hh; i += 256) h1s[i] = bf2f(h1b[b * Hh + i]);
    __syncthreads();

    // atth[a] = att_bh[a] + sum_k h1[k] * Wh[k][a]  (WhT rows contiguous in k)
    for (int a = tid; a < Aa; a += 256) {
        const ushort* wr = attWh_t + (size_t)a * Hh;
        float s = att_bh[a];
#pragma unroll 4
        for (int k0 = 0; k0 < Hh; k0 += 8) {
            bhalf8 w = *(const bhalf8*)(wr + k0);
#pragma unroll
            for (int jj = 0; jj < 8; ++jj) s += h1s[k0 + jj] * bf2f((ushort)w[jj]);
        }
        atth[a] = s;
    }
    __syncthreads();

    // scores[p] = sum_a tanh(feat_att + atth) * v ; lane owns a = lane*8..+7
    float attv8[8], atth8[8];
#pragma unroll
    for (int jj = 0; jj < 8; ++jj) { attv8[jj] = att_v[lane * 8 + jj]; atth8[jj] = atth[lane * 8 + jj]; }
    const ushort* fa = feat_att + (size_t)b * Pp * Aa;
    for (int p = wave; p < Pp; p += 4) {
        bhalf8 v = *(const bhalf8*)(fa + (size_t)p * Aa + lane * 8);
        float partial = 0.f;
#pragma unroll
        for (int jj = 0; jj < 8; ++jj) partial += tanh_(bf2f((ushort)v[jj]) + atth8[jj]) * attv8[jj];
#pragma unroll
        for (int o = 32; o > 0; o >>= 1) partial += __shfl_down(partial, o);
        if (lane == 0) sc[p] = partial + att_bv[0];
    }
    __syncthreads();

    if (tid < 64) { // single-wave softmax over P=196
        float m = -1e30f;
        for (int p = lane; p < Pp; p += 64) m = fmaxf(m, sc[p]);
#pragma unroll
        for (int o = 32; o > 0; o >>= 1) m = fmaxf(m, __shfl_down(m, o));
        m = __shfl(m, 0);
        float s = 0.f;
        for (int p = lane; p < Pp; p += 64) { float e = __expf(sc[p] - m); sc[p] = e; s += e; }
#pragma unroll
        for (int o = 32; o > 0; o >>= 1) s += __shfl_down(s, o);
        s = __shfl(s, 0);
        float inv = 1.f / s;
        for (int p = lane; p < Pp; p += 64) sc[p] *= inv;
    }
    __syncthreads();

    // ctx = relu(alpha @ fproj + proj_b) -> xs ctx slot (bf16)
    const ushort* fp = fproj + (size_t)b * Pp * Hh;
    for (int h = tid; h < Hh; h += 256) {
        float s = 0.f;
#pragma unroll 4
        for (int p = 0; p < Pp; ++p) s += sc[p] * bf2f(fp[(size_t)p * Hh + h]);
        s += proj_b[h];
        xs_t[(size_t)b * XS + Ee + Hh + h] = f2bf(fmaxf(s, 0.f));
    }
}

// ---------------------------------------------------------------------------
// fp32 [R,C] -> bf16 [C,R] transpose (32x32 LDS tile)
__global__ __launch_bounds__(256) void transpose_f32_bf16(
    const float* __restrict__ in, ushort* __restrict__ out, int R, int C)
{
    __shared__ float tile[32][33];
    const int tx = threadIdx.x & 31, ty = threadIdx.x >> 5;
    const int c0 = blockIdx.x * 32, r0 = blockIdx.y * 32;
    for (int i = ty; i < 32; i += 8) {
        int r = r0 + i, c = c0 + tx;
        tile[i][tx] = (r < R && c < C) ? in[(size_t)r * C + c] : 0.f;
    }
    __syncthreads();
    for (int i = ty; i < 32; i += 8) {
        int oc = c0 + i, orr = r0 + tx;
        if (oc < C && orr < R) out[(size_t)oc * R + orr] = f2bf(tile[tx][i]);
    }
}

// strided fp32 -> bf16 convert: out[r*C+c] = in[r*inld + c0 + c]
__global__ __launch_bounds__(256) void convert_slice_kernel(
    const float* __restrict__ in, int inld, int c0,
    ushort* __restrict__ out, int R, int C)
{
    int idx = blockIdx.x * 256 + threadIdx.x;
    if (idx >= R * C) return;
    int r = idx / C, c = idx - r * C;
    out[idx] = f2bf(in[(size_t)r * inld + c0 + c]);
}

// embedding gather -> xs emb slot (bf16)
__global__ __launch_bounds__(256) void emb_fill_kernel(
    const float* __restrict__ emb, const int* __restrict__ captions,
    ushort* __restrict__ xs)
{
    int idx = blockIdx.x * 256 + threadIdx.x;
    if (idx >= Tt * Bb * Ee) return;
    int e = idx % Ee, rb = idx / Ee;
    int t = rb / Bb, b = rb % Bb;
    int tok = captions[b * Tt + t];
    xs[((size_t)(t * Bb + b)) * XS + Ee + e] = f2bf(emb[(size_t)tok * Ee + e]);
}

// LayerNorm rows of 512, fp32 in -> bf16 out
__global__ __launch_bounds__(256) void layernorm_kernel(
    const float* __restrict__ x, const float* __restrict__ g,
    const float* __restrict__ beta, ushort* __restrict__ y)
{
    __shared__ float red[4];
    const int row = blockIdx.x;
    const float* xr = x + (size_t)row * Hh;
    const int tid = threadIdx.x, lane = tid & 63, wave = tid >> 6;
    float v0 = xr[tid], v1 = xr[tid + 256];
    float s = v0 + v1;
#pragma unroll
    for (int o = 32; o > 0; o >>= 1) s += __shfl_down(s, o);
    if (lane == 0) red[wave] = s;
    __syncthreads();
    float mu = (red[0] + red[1] + red[2] + red[3]) / 512.f;
    float d0 = v0 - mu, d1 = v1 - mu;
    float q = d0 * d0 + d1 * d1;
#pragma unroll
    for (int o = 32; o > 0; o >>= 1) q += __shfl_down(q, o);
    __syncthreads();
    if (lane == 0) red[wave] = q;
    __syncthreads();
    float var = (red[0] + red[1] + red[2] + red[3]) / 512.f;
    float inv = 1.f / sqrtf(var + 1e-5f);
    y[(size_t)row * Hh + tid]       = f2bf(d0 * inv * g[tid] + beta[tid]);
    y[(size_t)row * Hh + tid + 256] = f2bf(d1 * inv * g[tid + 256] + beta[tid + 256]);
}

// ---------------------------------------------------------------------------
extern "C" void kernel_launch(void* const* d_in, const int* in_sizes, int n_in,
                              void* d_out, int out_size, void* d_ws, size_t ws_size,
                              hipStream_t stream)
{
    const float* features = (const float*)d_in[0];
    const int*   captions = (const int*)d_in[1];
    const float* emb      = (const float*)d_in[2];
    const float* att_Wf   = (const float*)d_in[3];
    const float* att_bf   = (const float*)d_in[4];
    const float* att_Wh   = (const float*)d_in[5];
    const float* att_bh   = (const float*)d_in[6];
    const float* att_v    = (const float*)d_in[7];
    const float* att_bv   = (const float*)d_in[8];
    const float* proj_W   = (const float*)d_in[9];
    const float* proj_b   = (const float*)d_in[10];
    const float* W_ih0    = (const float*)d_in[11];
    const float* W_hh0    = (const float*)d_in[12];
    const float* b_ih0    = (const float*)d_in[13];
    const float* b_hh0    = (const float*)d_in[14];
    const float* W_ih1    = (const float*)d_in[15];
    const float* W_hh1    = (const float*)d_in[16];
    const float* b_ih1    = (const float*)d_in[17];
    const float* b_hh1    = (const float*)d_in[18];
    const float* ln_g     = (const float*)d_in[19];
    const float* ln_b     = (const float*)d_in[20];
    const float* skip_W   = (const float*)d_in[21];
    const float* skip_b   = (const float*)d_in[22];
    const float* fc_W     = (const float*)d_in[23];
    const float* fc_b     = (const float*)d_in[24];

    // byte bump-allocator over d_ws (~122 MB total; 137 MB proven available)
    char* base = (char*)d_ws;
    size_t off = 0;
    auto alloc = [&](size_t bytes) { char* p = base + off; off = (off + bytes + 255) & ~(size_t)255; return p; };

    float*  c0      = (float*)alloc(Bb * Hh * 4);
    float*  c1      = (float*)alloc(Bb * Hh * 4);
    ushort* h0b[2]  = {(ushort*)alloc(Bb * Hh * 2), (ushort*)alloc(Bb * Hh * 2)};
    ushort* h1b[2]  = {(ushort*)alloc(Bb * Hh * 2), (ushort*)alloc(Bb * Hh * 2)};
    size_t state_bytes = off; // zero everything above in one memset

    ushort* attWf_t  = (ushort*)alloc((size_t)Aa * Ff * 2);      // [512,2048]
    ushort* projW_t  = (ushort*)alloc((size_t)Hh * Ff * 2);      // [512,2048]
    ushort* attWh_t  = (ushort*)alloc((size_t)Aa * Hh * 2);      // [512,512]
    ushort* skipW_t  = (ushort*)alloc((size_t)Hh * XS * 2);      // [512,1536]
    ushort* fcW_t    = (ushort*)alloc((size_t)Vv * Hh * 2);      // [10000,512]
    ushort* Wemb0    = (ushort*)alloc((size_t)4 * Hh * Ee * 2);  // [2048,512]
    ushort* Wctx0    = (ushort*)alloc((size_t)4 * Hh * Hh * 2);
    ushort* Whh0     = (ushort*)alloc((size_t)4 * Hh * Hh * 2);
    ushort* Wih1     = (ushort*)alloc((size_t)4 * Hh * Hh * 2);
    ushort* Whh1     = (ushort*)alloc((size_t)4 * Hh * Hh * 2);
    ushort* feat_ab  = (ushort*)alloc((size_t)Bb * Pp * Aa * 2); // [25088,512]
    ushort* fproj_b  = (ushort*)alloc((size_t)Bb * Pp * Hh * 2);
    ushort* xs       = (ushort*)alloc((size_t)Tt * Bb * XS * 2); // [3072,1536]
    float*  g0pre    = (float*)alloc((size_t)Tt * Bb * 4 * Hh * 4); // [3072,2048]
    float*  skip_pre = (float*)alloc((size_t)Tt * Bb * Hh * 4);
    ushort* ln_all   = (ushort*)alloc((size_t)Tt * Bb * Hh * 2);

    hipMemsetAsync(d_ws, 0, state_bytes, stream); // zero c0,c1,h0b,h1b

    dim3 blk(256);

    // ---- one-time weight prep ----
    transpose_f32_bf16<<<dim3(Aa / 32, Ff / 32), blk, 0, stream>>>(att_Wf, attWf_t, Ff, Aa);
    transpose_f32_bf16<<<dim3(Hh / 32, Ff / 32), blk, 0, stream>>>(proj_W, projW_t, Ff, Hh);
    transpose_f32_bf16<<<dim3(Aa / 32, Hh / 32), blk, 0, stream>>>(att_Wh, attWh_t, Hh, Aa);
    transpose_f32_bf16<<<dim3(Hh / 32, XS / 32), blk, 0, stream>>>(skip_W, skipW_t, XS, Hh);
    transpose_f32_bf16<<<dim3((Vv + 31) / 32, Hh / 32), blk, 0, stream>>>(fc_W, fcW_t, Hh, Vv);
    int nW = 4 * Hh * Hh; // 1M elems
    convert_slice_kernel<<<(nW + 255) / 256, blk, 0, stream>>>(W_ih0, Ee + Hh, 0,  Wemb0, 4 * Hh, Ee);
    convert_slice_kernel<<<(nW + 255) / 256, blk, 0, stream>>>(W_ih0, Ee + Hh, Ee, Wctx0, 4 * Hh, Hh);
    convert_slice_kernel<<<(nW + 255) / 256, blk, 0, stream>>>(W_hh0, Hh, 0, Whh0, 4 * Hh, Hh);
    convert_slice_kernel<<<(nW + 255) / 256, blk, 0, stream>>>(W_ih1, Hh, 0, Wih1, 4 * Hh, Hh);
    convert_slice_kernel<<<(nW + 255) / 256, blk, 0, stream>>>(W_hh1, Hh, 0, Whh1, 4 * Hh, Hh);

    emb_fill_kernel<<<(Tt * Bb * Ee + 255) / 256, blk, 0, stream>>>(emb, captions, xs);

    // ---- big precompute GEMMs (A = fp32 features, converted in-flight) ----
    mfma_gemm<true, 1><<<dim3(Bb * Pp / 64, Aa / 64), blk, 0, stream>>>(
        features, Ff, attWf_t, Ff, Ff, att_bf, nullptr, feat_ab, Aa, Aa);
    mfma_gemm<true, 1><<<dim3(Bb * Pp / 64, Hh / 64), blk, 0, stream>>>(
        features, Ff, projW_t, Ff, Ff, nullptr, nullptr, fproj_b, Hh, Hh);

    // gates0 emb-part + both biases, hoisted for all t: [3072,512]@[512,2048]
    mfma_gemm<false, 0><<<dim3(Tt * Bb / 64, 4 * Hh / 64), blk, 0, stream>>>(
        xs + Ee, XS, Wemb0, Ee, Ee, b_ih0, b_hh0, g0pre, 4 * Hh, 4 * Hh);

    // ---- sequential decode loop: 3 kernels/step ----
    int cur0 = 0, cur1 = 0;
    for (int t = 0; t < Tt; ++t) {
        ushort* xs_t = xs + (size_t)t * Bb * XS;

        attention_step_kernel<<<Bb, blk, 0, stream>>>(
            feat_ab, fproj_b, h1b[cur1], attWh_t, att_bh, att_v, att_bv, proj_b, xs_t);

        gates_cell_kernel<true><<<dim3(Bb / 64, Hh / 16), blk, 0, stream>>>(
            xs_t + Ee + Hh, XS, Wctx0,         // A1 = ctx slot
            h0b[cur0], Whh0,                    // A2 = h0 (prev)
            g0pre + (size_t)t * Bb * 4 * Hh, nullptr, nullptr,
            c0, h0b[cur0 ^ 1], nullptr);

        gates_cell_kernel<false><<<dim3(Bb / 64, Hh / 16), blk, 0, stream>>>(
            h0b[cur0 ^ 1], Hh, Wih1,            // A1 = h0 (new)
            h1b[cur1], Whh1,                    // A2 = h1 (prev)
            nullptr, b_ih1, b_hh1,
            c1, h1b[cur1 ^ 1], xs_t);           // h1 -> state + xs[:,0:512]
        cur0 ^= 1; cur1 ^= 1;
    }

    // ---- tail: skip GEMM -> LN -> fc GEMM ----
    mfma_gemm<false, 0><<<dim3(Tt * Bb / 64, Hh / 64), blk, 0, stream>>>(
        xs, XS, skipW_t, XS, XS, skip_b, nullptr, skip_pre, Hh, Hh);

    layernorm_kernel<<<Tt * Bb, blk, 0, stream>>>(skip_pre, ln_g, ln_b, ln_all);

    mfma_gemm<false, 2><<<dim3(Tt * Bb / 64, (Vv + 63) / 64), blk, 0, stream>>>(
        ln_all, Hh, fcW_t, Hh, Hh, fc_b, nullptr, (float*)d_out, Vv, Vv);
}